// Round 1
// baseline (2912.569 us; speedup 1.0000x reference)
//
#include <hip/hip_runtime.h>
#include <stdint.h>

#define EPS 1e-3f

typedef _Float16 half2v __attribute__((ext_vector_type(2)));
typedef _Float16 half4v __attribute__((ext_vector_type(4)));
typedef unsigned int uint8v __attribute__((ext_vector_type(8)));

#if defined(__has_builtin)
#if __has_builtin(__builtin_amdgcn_fdot2)
#define HAVE_FDOT2 1
#endif
#endif
#ifndef HAVE_FDOT2
#define HAVE_FDOT2 0
#endif

__device__ __forceinline__ float fdot2f(half2v a, half2v b, float c) {
#if HAVE_FDOT2
  return __builtin_amdgcn_fdot2(a, b, c, false);
#else
  return c + (float)a.x * (float)b.x + (float)a.y * (float)b.y;
#endif
}

__device__ __forceinline__ half2v as_h2(unsigned int u) {
  union { unsigned int u; half2v h; } cv;
  cv.u = u;
  return cv.h;
}

// ---------------------------------------------------------------------------
// Setup: fold BN into per-channel scale/bias; repack w_pos into f16 [r][s][k][u]
// so one tap's 64 weights are 128 contiguous bytes (uniform -> s_load).
// ---------------------------------------------------------------------------
__global__ __launch_bounds__(256) void setup_kernel(
    const float* __restrict__ w_pos,
    const float* __restrict__ gq, const float* __restrict__ bq,
    const float* __restrict__ mq, const float* __restrict__ vq,
    const float* __restrict__ gv, const float* __restrict__ bv,
    const float* __restrict__ mv, const float* __restrict__ vvar,
    float* __restrict__ scale_bias, _Float16* __restrict__ whp) {
  const int idx = blockIdx.x * 256 + threadIdx.x;
  if (idx < 384) {
    float sc, bi;
    if (idx < 64) {
      const float inv = gq[idx] * rsqrtf(vq[idx] + EPS);
      sc = inv; bi = bq[idx] - mq[idx] * inv;
    } else if (idx < 128) {
      sc = 1.f; bi = 0.f;  // k has no BN
    } else {
      const int o = idx - 128;
      const float inv = gv[o] * rsqrtf(vvar[o] + EPS);
      sc = inv; bi = bv[o] - mv[o] * inv;
    }
    scale_bias[idx] = sc;
    scale_bias[384 + idx] = bi;
  }
  if (idx < 33856) {  // 529 taps * 16 k * 4 u
    const int u = idx & 3;
    const int kk = (idx >> 2) & 15;
    const int rs = idx >> 6;  // 0..528
    const int r = rs / 23, s = rs - r * 23;
    // w_pos layout [k][u][1][r][s]
    whp[idx] = (_Float16)w_pos[kk * 2116 + u * 529 + r * 23 + s];
  }
}

// ---------------------------------------------------------------------------
// Projection GEMM: proj[b][o][n] = W[o][:] . x[b][:][n], o in [0,384)
//   o<64: q (BN folded), 64..128: k raw, 128..384: v (BN folded)
// 64x64 tile, 4x4 microtile, BK=32, fp32.
// ---------------------------------------------------------------------------
__global__ __launch_bounds__(256) void proj_gemm(
    const float* __restrict__ x,
    const float* __restrict__ w_q, const float* __restrict__ w_k,
    const float* __restrict__ w_v,
    const float* __restrict__ scale_bias,
    float* __restrict__ proj) {
  const int b = blockIdx.z;
  const int ot = blockIdx.y;          // 0..5 (64-row slabs of the 384 outputs)
  const int nBase = blockIdx.x * 64;
  const int tid = threadIdx.x;
  const int tx = tid & 15, ty = tid >> 4;

  const float* W;
  int oRow;
  if (ot == 0)      { W = w_q; oRow = 0; }
  else if (ot == 1) { W = w_k; oRow = 0; }
  else              { W = w_v; oRow = (ot - 2) * 64; }

  __shared__ float la[32][64];  // [k][o]
  __shared__ float lb[32][64];  // [k][n]

  float acc[4][4];
#pragma unroll
  for (int i = 0; i < 4; i++)
#pragma unroll
    for (int j = 0; j < 4; j++) acc[i][j] = 0.f;

  const int o_l = tid & 63;
  const int c4a = (tid >> 6) * 4;  // 0,4,8,12
  const int cb = tid >> 4;         // 0..15
  const int n4 = (tid & 15) * 4;

  for (int k0 = 0; k0 < 256; k0 += 32) {
    __syncthreads();
#pragma unroll
    for (int rr = 0; rr < 2; rr++) {
      const int c0 = c4a + rr * 16;
      const float4 wv4 = *(const float4*)&W[(size_t)(oRow + o_l) * 256 + k0 + c0];
      la[c0 + 0][o_l] = wv4.x;
      la[c0 + 1][o_l] = wv4.y;
      la[c0 + 2][o_l] = wv4.z;
      la[c0 + 3][o_l] = wv4.w;
    }
#pragma unroll
    for (int rr = 0; rr < 2; rr++) {
      const int c_l = cb + rr * 16;
      const float4 xv =
          *(const float4*)&x[((size_t)(b * 256 + k0 + c_l)) * 4096 + nBase + n4];
      *(float4*)&lb[c_l][n4] = xv;
    }
    __syncthreads();
#pragma unroll
    for (int kk = 0; kk < 32; kk++) {
      const float4 av = *(const float4*)&la[kk][ty * 4];
      const float4 bv = *(const float4*)&lb[kk][tx * 4];
      const float a[4] = {av.x, av.y, av.z, av.w};
      const float bb[4] = {bv.x, bv.y, bv.z, bv.w};
#pragma unroll
      for (int i = 0; i < 4; i++)
#pragma unroll
        for (int j = 0; j < 4; j++) acc[i][j] = fmaf(a[i], bb[j], acc[i][j]);
    }
  }

#pragma unroll
  for (int i = 0; i < 4; i++) {
    const int oG = ot * 64 + ty * 4 + i;
    const float sc = scale_bias[oG];
    const float bi = scale_bias[384 + oG];
    float4 r;
    r.x = fmaf(acc[i][0], sc, bi);
    r.y = fmaf(acc[i][1], sc, bi);
    r.z = fmaf(acc[i][2], sc, bi);
    r.w = fmaf(acc[i][3], sc, bi);
    *(float4*)&proj[((size_t)(b * 384 + oG)) * 4096 + nBase + tx * 4] = r;
  }
}

// ---------------------------------------------------------------------------
// Softmax over n=4096, in place on the k section of proj (channels 64..128).
// One block per (b,u,kk) row.
// ---------------------------------------------------------------------------
__global__ __launch_bounds__(256) void softmax_k(float* __restrict__ proj) {
  const int row = blockIdx.x;  // 0..1023
  const int b = row >> 6, c = row & 63;
  float* p = proj + ((size_t)(b * 384 + 64 + c)) * 4096;
  const int tid = threadIdx.x;

  float4 v[4];
  float vmax = -3.4e38f;
#pragma unroll
  for (int i = 0; i < 4; i++) {
    v[i] = ((const float4*)p)[tid + i * 256];
    vmax = fmaxf(vmax, fmaxf(fmaxf(v[i].x, v[i].y), fmaxf(v[i].z, v[i].w)));
  }
#pragma unroll
  for (int off = 32; off > 0; off >>= 1) vmax = fmaxf(vmax, __shfl_xor(vmax, off));
  __shared__ float redm[4], reds[4];
  if ((tid & 63) == 0) redm[tid >> 6] = vmax;
  __syncthreads();
  vmax = fmaxf(fmaxf(redm[0], redm[1]), fmaxf(redm[2], redm[3]));

  float sum = 0.f;
#pragma unroll
  for (int i = 0; i < 4; i++) {
    v[i].x = expf(v[i].x - vmax); sum += v[i].x;
    v[i].y = expf(v[i].y - vmax); sum += v[i].y;
    v[i].z = expf(v[i].z - vmax); sum += v[i].z;
    v[i].w = expf(v[i].w - vmax); sum += v[i].w;
  }
#pragma unroll
  for (int off = 32; off > 0; off >>= 1) sum += __shfl_xor(sum, off);
  if ((tid & 63) == 0) reds[tid >> 6] = sum;
  __syncthreads();
  sum = reds[0] + reds[1] + reds[2] + reds[3];
  const float inv = 1.f / sum;
#pragma unroll
  for (int i = 0; i < 4; i++) {
    v[i].x *= inv; v[i].y *= inv; v[i].z *= inv; v[i].w *= inv;
    ((float4*)p)[tid + i * 256] = v[i];
  }
}

// ---------------------------------------------------------------------------
// Lc[b][kk][dv] = sum_u sum_m ksm[b,u,kk,m] * v[b,u,dv,m]
// Block = (kk, b); wave w covers dv = w*16..w*16+15; lanes stride m.
// ---------------------------------------------------------------------------
__global__ __launch_bounds__(256) void lc_kernel(const float* __restrict__ proj,
                                                 float* __restrict__ Lc) {
  const int kk = blockIdx.x, b = blockIdx.y;
  const int tid = threadIdx.x;
  const int wave = tid >> 6, lane = tid & 63;
  float acc[16];
#pragma unroll
  for (int j = 0; j < 16; j++) acc[j] = 0.f;

  for (int u = 0; u < 4; u++) {
    const float* ks = proj + ((size_t)(b * 384 + 64 + u * 16 + kk)) * 4096;
    const float* vp = proj + ((size_t)(b * 384 + 128 + u * 64 + wave * 16)) * 4096;
    for (int m = lane; m < 4096; m += 64) {
      const float kvl = ks[m];
#pragma unroll
      for (int j = 0; j < 16; j++)
        acc[j] = fmaf(kvl, vp[(size_t)j * 4096 + m], acc[j]);
    }
  }
#pragma unroll
  for (int j = 0; j < 16; j++) {
#pragma unroll
    for (int off = 32; off > 0; off >>= 1) acc[j] += __shfl_xor(acc[j], off);
  }
  if (lane == 0) {
#pragma unroll
    for (int j = 0; j < 16; j++)
      Lc[(b * 16 + kk) * 64 + wave * 16 + j] = acc[j];
  }
}

// ---------------------------------------------------------------------------
// Fused position-conv + Yp + Yc + output transpose.
// Block = (dv, b, half). LDS holds v (4 u planes, f16, interleaved [row][col][u])
// with zero halo: 54 rows x 86 cols x 4 u. Per tap: 1 ds_read_b64 + 32 v_dot2.
// Epilogue contracts acc+Lc+b_pos with q and writes out[b][h*64+dv][n].
// ---------------------------------------------------------------------------
__global__ __launch_bounds__(256) void lambda_conv(
    const float* __restrict__ proj, const _Float16* __restrict__ whp,
    const float* __restrict__ Lc, const float* __restrict__ b_pos,
    float* __restrict__ out) {
  const int dv = blockIdx.x;
  const int b = blockIdx.y;
  const int hf = blockIdx.z;  // which 32-row half of the image
  const int tid = threadIdx.x;

  __shared__ _Float16 lds[54 * 86 * 4];

  // zero (covers halo)
  for (int i = tid; i < (54 * 86 * 4) / 2; i += 256) ((unsigned int*)lds)[i] = 0u;
  __syncthreads();

  // stage v planes (fp32 -> f16), u interleaved
  {
    const float* vp0 = proj + ((size_t)(b * 384 + 128 + dv)) * 4096;
    const int g0 = hf * 32 - 11;
    for (int idx = tid; idx < 54 * 64; idx += 256) {
      const int lr = idx >> 6, cc = idx & 63;
      const int g = g0 + lr;
      if (g >= 0 && g < 64) {
        const float* vp = vp0 + g * 64 + cc;
        half4v hv;
        hv.x = (_Float16)vp[0];
        hv.y = (_Float16)vp[64 * 4096];
        hv.z = (_Float16)vp[128 * 4096];
        hv.w = (_Float16)vp[192 * 4096];
        *(half4v*)&lds[(lr * 86 + cc + 11) * 4] = hv;
      }
    }
  }
  __syncthreads();

  float lcb[16];
#pragma unroll
  for (int kk = 0; kk < 16; kk++)
    lcb[kk] = Lc[(b * 16 + kk) * 64 + dv] + b_pos[kk];

  for (int pass = 0; pass < 8; pass++) {
    const int nl = pass * 256 + tid;
    const int hl = nl >> 6;  // local row 0..31
    const int w = nl & 63;

    float acc[16];
#pragma unroll
    for (int kk = 0; kk < 16; kk++) acc[kk] = 0.f;

    for (int r = 0; r < 23; r++) {
      const int rowbase = (hl + r) * 86 + w;
      for (int s = 0; s < 23; s++) {
        const half4v vv = *(const half4v*)&lds[(rowbase + s) * 4];
        const uint8v* wt8 = (const uint8v*)(whp + ((r * 23 + s) << 6));
#pragma unroll
        for (int k4 = 0; k4 < 4; k4++) {
          const uint8v wblk = wt8[k4];  // 4 k-channels, uniform -> s_load
          acc[k4 * 4 + 0] = fdot2f(vv.xy, as_h2(wblk[0]), acc[k4 * 4 + 0]);
          acc[k4 * 4 + 0] = fdot2f(vv.zw, as_h2(wblk[1]), acc[k4 * 4 + 0]);
          acc[k4 * 4 + 1] = fdot2f(vv.xy, as_h2(wblk[2]), acc[k4 * 4 + 1]);
          acc[k4 * 4 + 1] = fdot2f(vv.zw, as_h2(wblk[3]), acc[k4 * 4 + 1]);
          acc[k4 * 4 + 2] = fdot2f(vv.xy, as_h2(wblk[4]), acc[k4 * 4 + 2]);
          acc[k4 * 4 + 2] = fdot2f(vv.zw, as_h2(wblk[5]), acc[k4 * 4 + 2]);
          acc[k4 * 4 + 3] = fdot2f(vv.xy, as_h2(wblk[6]), acc[k4 * 4 + 3]);
          acc[k4 * 4 + 3] = fdot2f(vv.zw, as_h2(wblk[7]), acc[k4 * 4 + 3]);
        }
      }
    }

    // epilogue: Y[b,n,h,dv] = sum_k q[b,h,k,n] * (Lp + b_pos + Lc)
    const int h_img = hf * 32 + hl;
    const int n = h_img * 64 + w;
    const float* qb = proj + ((size_t)(b * 384)) * 4096 + n;
    float y[4] = {0.f, 0.f, 0.f, 0.f};
#pragma unroll
    for (int kk = 0; kk < 16; kk++) {
      const float coeff = acc[kk] + lcb[kk];
#pragma unroll
      for (int hh = 0; hh < 4; hh++)
        y[hh] = fmaf(qb[(size_t)(hh * 16 + kk) * 4096], coeff, y[hh]);
    }
#pragma unroll
    for (int hh = 0; hh < 4; hh++)
      out[((size_t)(b * 256 + hh * 64 + dv)) * 4096 + n] = y[hh];
  }
}

// ---------------------------------------------------------------------------
extern "C" void kernel_launch(void* const* d_in, const int* in_sizes, int n_in,
                              void* d_out, int out_size, void* d_ws, size_t ws_size,
                              hipStream_t stream) {
  const float* x       = (const float*)d_in[0];
  const float* w_q     = (const float*)d_in[1];
  const float* w_k     = (const float*)d_in[2];
  const float* w_v     = (const float*)d_in[3];
  const float* gamma_q = (const float*)d_in[4];
  const float* beta_q  = (const float*)d_in[5];
  const float* mean_q  = (const float*)d_in[6];
  const float* var_q   = (const float*)d_in[7];
  const float* gamma_v = (const float*)d_in[8];
  const float* beta_v  = (const float*)d_in[9];
  const float* mean_v  = (const float*)d_in[10];
  const float* var_v   = (const float*)d_in[11];
  const float* w_pos   = (const float*)d_in[12];
  const float* b_pos   = (const float*)d_in[13];

  float* ws = (float*)d_ws;
  float* proj = ws;                            // 16*384*4096 = 25165824 floats
  float* sb   = ws + 25165824;                 // 768 floats
  float* Lc   = sb + 768;                      // 16384 floats
  _Float16* whp = (_Float16*)(Lc + 16384);     // 33856 halfs (128B-aligned)
  float* out = (float*)d_out;

  setup_kernel<<<133, 256, 0, stream>>>(w_pos, gamma_q, beta_q, mean_q, var_q,
                                        gamma_v, beta_v, mean_v, var_v, sb, whp);
  proj_gemm<<<dim3(64, 6, 16), 256, 0, stream>>>(x, w_q, w_k, w_v, sb, proj);
  softmax_k<<<1024, 256, 0, stream>>>(proj);
  lc_kernel<<<dim3(16, 16), 256, 0, stream>>>(proj, Lc);
  lambda_conv<<<dim3(64, 16, 2), 256, 0, stream>>>(proj, whp, Lc, b_pos, out);
}